// Round 10
// baseline (395.121 us; speedup 1.0000x reference)
//
#include <hip/hip_runtime.h>
#include <hip/hip_bf16.h>
#include <stdint.h>

#define N_NODES  50000
#define N_EDGES  800000
#define N_GRAPHS 512

#define BINSZ   128
#define NBIN    ((N_NODES + BINSZ - 1)/BINSZ)    // 391
#define NCHUNK  256
#define CHUNK   ((N_EDGES + NCHUNK - 1)/NCHUNK)  // 3125
#define MAXBIN  3072                             // per-bin capacity (mean 2048 + 22 sigma)

typedef __attribute__((ext_vector_type(8))) short  short8;
typedef __attribute__((ext_vector_type(4))) float  floatx4;
typedef unsigned short u16;
typedef unsigned int   u32;

__device__ __forceinline__ u16 f2b(float f){
  u32 u = __float_as_uint(f);
  u = (u + 0x7FFFu + ((u >> 16) & 1u)) >> 16;   // RNE
  return (u16)u;
}
__device__ __forceinline__ u32 pack2(float a, float b){
  return (u32)f2b(a) | ((u32)f2b(b) << 16);
}
__device__ __forceinline__ float blo(u32 v){ return __uint_as_float(v << 16); }
__device__ __forceinline__ float bhi(u32 v){ return __uint_as_float(v & 0xFFFF0000u); }
__device__ __forceinline__ float b2f(u16 s){ return __uint_as_float(((u32)s) << 16); }

// ---- fused prep: cast X, weights (3 conv layers + MLP), bounds, bincur, zero PM/PX
#define PREP_CAST   6250
#define PREP_W      (PREP_CAST + 384)   // 3*128*256 elems
#define PREP_MLP    (PREP_W + 128)      // 2*128*128 elems
#define PREP_BND    (PREP_MLP + 3)
#define PREP_CUR    (PREP_BND + 2)
#define PREP_ZERO   (PREP_CUR + 512)    // 131072 f32 (PM|PX contiguous)
__global__ void k_prep(const float4* __restrict__ x, uint2* __restrict__ X1,
                       const float* __restrict__ Wrel1, const float* __restrict__ Wroot1,
                       const float* __restrict__ Wrel2, const float* __restrict__ Wroot2,
                       const float* __restrict__ Wrel3, const float* __restrict__ Wroot3,
                       u16* __restrict__ wcat,
                       const float* __restrict__ W1, const float* __restrict__ W2,
                       u16* __restrict__ wm,
                       const int* __restrict__ batch, int* __restrict__ start,
                       int* __restrict__ bincur, float* __restrict__ PMz){
  int blk = blockIdx.x, t = threadIdx.x;
  if (blk < PREP_CAST){
    int i = blk*256 + t;                       // exactly 1,600,000
    float4 v = x[i];
    X1[i] = make_uint2(pack2(v.x, v.y), pack2(v.z, v.w));
  } else if (blk < PREP_W){
    int id = (blk - PREP_CAST)*256 + t;        // 98304
    int l = id >> 15;
    int r = id & 32767;
    int n = r >> 8;
    int k = r & 255;
    const float* Wrel  = (l==0) ? Wrel1  : (l==1) ? Wrel2  : Wrel3;
    const float* Wroot = (l==0) ? Wroot1 : (l==1) ? Wroot2 : Wroot3;
    float w = (k < 128) ? Wrel[k*128 + n] : Wroot[(k-128)*128 + n];
    int c = k >> 3, j = k & 7;
    wcat[l*32768 + n*256 + ((c ^ (n & 15)) << 3) + j] = f2b(w);
  } else if (blk < PREP_MLP){
    int id = (blk - PREP_W)*256 + t;           // 32768
    int l = id >> 14;
    int r = id & 16383;
    int n = r >> 7;
    int k = r & 127;
    const float* W = l ? W2 : W1;
    wm[l*16384 + n*128 + k] = f2b(W[k*128 + n]);
  } else if (blk < PREP_BND){
    int g = (blk - PREP_MLP)*256 + t;
    if (g <= N_GRAPHS){
      int lo = 0, hi = N_NODES;
      while (lo < hi){ int mid = (lo + hi) >> 1; if (batch[mid] < g) lo = mid + 1; else hi = mid; }
      start[g] = lo;
    }
  } else if (blk < PREP_CUR){
    int i = (blk - PREP_BND)*256 + t;
    if (i < NBIN) bincur[i] = i*MAXBIN;
  } else {
    int i = (blk - PREP_CUR)*256 + t;          // 131072 exactly
    PMz[i] = 0.f;
  }
}

// ---- CSR step 1: fused hist + range-reserve + scatter -----------------------
__launch_bounds__(256)
__global__ void k_scatter2(const int* __restrict__ src, const int* __restrict__ dst,
                           int* __restrict__ bincur, u32* __restrict__ rec){
  __shared__ int h[NBIN];
  __shared__ int cur[NBIN];
  int t = threadIdx.x;
  for (int i = t; i < NBIN; i += 256) h[i] = 0;
  __syncthreads();
  int base = blockIdx.x*CHUNK;
  int end  = min(base + CHUNK, N_EDGES);
  for (int i = base + t; i < end; i += 256) atomicAdd(&h[dst[i] >> 7], 1);
  __syncthreads();
  for (int i = t; i < NBIN; i += 256){
    int c = h[i];
    cur[i] = c ? atomicAdd(&bincur[i], c) : 0;
  }
  __syncthreads();
  for (int i = base + t; i < end; i += 256){
    int d = dst[i], sv = src[i];
    int b = d >> 7;
    int p = atomicAdd(&cur[b], 1);
    rec[p] = (u32)(((d & 127) << 16) | sv);
  }
}

// ---- CSR step 2: per-bin node-ordered segment; rp[node] = (start<<11)|deg ---
__global__ void k_bincsr(const u32* __restrict__ rec, const int* __restrict__ bincur,
                         u32* __restrict__ rp, int* __restrict__ col){
  __shared__ u32 recs[MAXBIN];
  __shared__ int colL[MAXBIN];
  __shared__ int deg[BINSZ];
  __shared__ int cursor[BINSZ];
  __shared__ int sc[BINSZ];
  int b = blockIdx.x, t = threadIdx.x;
  int s0 = b*MAXBIN;
  int n = bincur[b] - s0;
  if (t < BINSZ) deg[t] = 0;
  for (int i = t; i < n; i += 256) recs[i] = rec[s0 + i];
  __syncthreads();
  for (int i = t; i < n; i += 256) atomicAdd(&deg[(recs[i] >> 16) & 127], 1);
  __syncthreads();
  if (t < BINSZ) sc[t] = deg[t];
  __syncthreads();
  for (int off = 1; off < BINSZ; off <<= 1){
    int u = 0;
    if (t < BINSZ && t >= off) u = sc[t - off];
    __syncthreads();
    if (t < BINSZ) sc[t] += u;
    __syncthreads();
  }
  if (t < BINSZ){
    int d = deg[t];
    int pref = sc[t] - d;
    cursor[t] = pref;
    int node = b*BINSZ + t;
    if (node < N_NODES) rp[node] = (u32)((s0 + pref) << 11) | (u32)min(d, 2047);
  }
  __syncthreads();
  for (int i = t; i < n; i += 256){
    u32 r = recs[i];
    int p = atomicAdd(&cursor[(r >> 16) & 127], 1);
    colL[p] = (int)(r & 0xFFFFu);
  }
  __syncthreads();
  for (int i = t; i < n; i += 256) col[s0 + i] = colL[i];
}

// ---- Aggregation: M[i] = (1/deg) * sum_{j in N(i)} X[j]  (bf16 out) --------
__global__ void k_aggm(const u16* __restrict__ X, const u32* __restrict__ rp,
                       const int* __restrict__ col, u16* __restrict__ M){
  int wave = threadIdx.x >> 6, lane = threadIdx.x & 63;
  int node = blockIdx.x*4 + wave;                 // grid covers exactly 50000
  u32 r = rp[node];
  int s = (int)(r >> 11), d = (int)(r & 2047);
  int e = s + d;
  int sub = lane >> 5, ln = lane & 31;
  const uint2* Xu = (const uint2*)X;
  float a0 = 0.f, a1 = 0.f, a2 = 0.f, a3 = 0.f;
  for (int cb = s; cb < e; cb += 64){
    int cnt = min(64, e - cb);
    int idx = 0;
    if (cb + lane < e) idx = col[cb + lane];
    int k = 0;
    for (; k + 4 <= cnt; k += 4){
      int jA = __shfl(idx, k + sub);
      int jB = __shfl(idx, k + 2 + sub);
      uint2 vA = Xu[jA*32 + ln];
      uint2 vB = Xu[jB*32 + ln];
      a0 += blo(vA.x); a1 += bhi(vA.x); a2 += blo(vA.y); a3 += bhi(vA.y);
      a0 += blo(vB.x); a1 += bhi(vB.x); a2 += blo(vB.y); a3 += bhi(vB.y);
    }
    for (; k + 2 <= cnt; k += 2){
      int j = __shfl(idx, k + sub);
      uint2 v = Xu[j*32 + ln];
      a0 += blo(v.x); a1 += bhi(v.x); a2 += blo(v.y); a3 += bhi(v.y);
    }
    if (k < cnt){
      int j = __shfl(idx, k);
      if (sub == 0){
        uint2 v = Xu[j*32 + ln];
        a0 += blo(v.x); a1 += bhi(v.x); a2 += blo(v.y); a3 += bhi(v.y);
      }
    }
  }
  a0 += __shfl_xor(a0, 32); a1 += __shfl_xor(a1, 32);
  a2 += __shfl_xor(a2, 32); a3 += __shfl_xor(a3, 32);
  if (sub == 0){
    float di = 1.0f / (float)max(d, 1);
    ((uint2*)M)[node*32 + ln] = make_uint2(pack2(a0*di, a1*di), pack2(a2*di, a3*di));
  }
}

// ---- layer-3: gather mean + atomic pool into PM; pool own X3 row into PX ----
__global__ void k_aggm3pool(const u16* __restrict__ X3, const u32* __restrict__ rp,
                            const int* __restrict__ col, const int* __restrict__ batch,
                            float* __restrict__ PM, float* __restrict__ PX){
  int wave = threadIdx.x >> 6, lane = threadIdx.x & 63;
  int node = blockIdx.x*4 + wave;                 // grid covers exactly 50000
  u32 r = rp[node];
  int s = (int)(r >> 11), d = (int)(r & 2047);
  int e = s + d;
  int sub = lane >> 5, ln = lane & 31;
  const uint2* Xu = (const uint2*)X3;
  float a0 = 0.f, a1 = 0.f, a2 = 0.f, a3 = 0.f;
  for (int cb = s; cb < e; cb += 64){
    int cnt = min(64, e - cb);
    int idx = 0;
    if (cb + lane < e) idx = col[cb + lane];
    int k = 0;
    for (; k + 4 <= cnt; k += 4){
      int jA = __shfl(idx, k + sub);
      int jB = __shfl(idx, k + 2 + sub);
      uint2 vA = Xu[jA*32 + ln];
      uint2 vB = Xu[jB*32 + ln];
      a0 += blo(vA.x); a1 += bhi(vA.x); a2 += blo(vA.y); a3 += bhi(vA.y);
      a0 += blo(vB.x); a1 += bhi(vB.x); a2 += blo(vB.y); a3 += bhi(vB.y);
    }
    for (; k + 2 <= cnt; k += 2){
      int j = __shfl(idx, k + sub);
      uint2 v = Xu[j*32 + ln];
      a0 += blo(v.x); a1 += bhi(v.x); a2 += blo(v.y); a3 += bhi(v.y);
    }
    if (k < cnt){
      int j = __shfl(idx, k);
      if (sub == 0){
        uint2 v = Xu[j*32 + ln];
        a0 += blo(v.x); a1 += bhi(v.x); a2 += blo(v.y); a3 += bhi(v.y);
      }
    }
  }
  a0 += __shfl_xor(a0, 32); a1 += __shfl_xor(a1, 32);
  a2 += __shfl_xor(a2, 32); a3 += __shfl_xor(a3, 32);
  int g = batch[node];
  if (sub == 0){
    float di = 1.0f / (float)max(d, 1);
    float* pm = PM + g*128 + ln*4;
    atomicAdd(pm + 0, a0*di);
    atomicAdd(pm + 1, a1*di);
    atomicAdd(pm + 2, a2*di);
    atomicAdd(pm + 3, a3*di);
  }
  u32 v = ((const u32*)X3)[node*64 + lane];
  atomicAdd(PX + g*128 + 2*lane,     blo(v));
  atomicAdd(PX + g*128 + 2*lane + 1, bhi(v));
}

// ---- GEMM: Xout = relu([M|X] @ Wcat + brel)  (M=50000, K=256, N=128) -------
// R5-proven form: B staged in 64KB swizzled LDS.
__launch_bounds__(256, 2)
__global__ void k_gemm2(const u16* __restrict__ M, const u16* __restrict__ X,
                        const u16* __restrict__ Wcat, const float* __restrict__ brel,
                        u16* __restrict__ Xout){
  __shared__ u16 Bs[128*256];
  {
    const uint4* s = (const uint4*)Wcat;
    uint4* d = (uint4*)Bs;
    #pragma unroll
    for (int i = 0; i < 16; i++) d[threadIdx.x + 256*i] = s[threadIdx.x + 256*i];
  }
  __syncthreads();

  int wave = threadIdx.x >> 6, lane = threadIdx.x & 63;
  int l15 = lane & 15, quad = lane >> 4;
  int wy = wave >> 1, wx = wave & 1;
  int rowBase = blockIdx.x*128 + wy*64;

  floatx4 acc[4][4] = {};

  #pragma unroll
  for (int k0 = 0; k0 < 256; k0 += 32){
    const u16* Asrc = (k0 < 128) ? M : X;
    int kk = k0 & 127;
    int c = (k0 >> 3) + quad;
    short8 a[4];
    #pragma unroll
    for (int mt = 0; mt < 4; mt++){
      int row = rowBase + mt*16 + l15;
      if (row > N_NODES-1) row = N_NODES-1;   // clamp; stores are masked
      a[mt] = *(const short8*)(Asrc + row*128 + kk + quad*8);
    }
    #pragma unroll
    for (int nt = 0; nt < 4; nt++){
      int n = wx*64 + nt*16 + l15;
      short8 b = *(const short8*)(Bs + n*256 + ((c ^ (n & 15)) << 3));
      #pragma unroll
      for (int mt = 0; mt < 4; mt++)
        acc[mt][nt] = __builtin_amdgcn_mfma_f32_16x16x32_bf16(a[mt], b, acc[mt][nt], 0, 0, 0);
    }
  }

  float bc[4];
  #pragma unroll
  for (int nt = 0; nt < 4; nt++) bc[nt] = brel[wx*64 + nt*16 + l15];

  #pragma unroll
  for (int mt = 0; mt < 4; mt++){
    int rbase = rowBase + mt*16 + quad*4;
    #pragma unroll
    for (int r = 0; r < 4; r++){
      int row = rbase + r;
      if (row < N_NODES){
        #pragma unroll
        for (int nt = 0; nt < 4; nt++){
          int n = wx*64 + nt*16 + l15;
          Xout[row*128 + n] = f2b(fmaxf(acc[mt][nt][r] + bc[nt], 0.f));
        }
      }
    }
  }
}

// ---- fused conv3 (MFMA on pooled sums) + 3-layer MLP ------------------------
#define APAD 136
__launch_bounds__(256)
__global__ void k_mlp2(const float* __restrict__ PM, const float* __restrict__ PX,
                       const int* __restrict__ start, const u16* __restrict__ wcat3,
                       const float* __restrict__ brel3, const u16* __restrict__ wm,
                       const float* __restrict__ b1, const float* __restrict__ b2,
                       const float* __restrict__ Wo, const float* __restrict__ bo,
                       float* __restrict__ out){
  __shared__ u16 Apad[128*APAD];
  int t = threadIdx.x;
  int wave = t >> 6, lane = t & 63;
  int l15 = lane & 15, quad = lane >> 4;
  int R = blockIdx.x*128;

  // ---- phase 0: Gb = [PM|PX]*ginv @ [Wrel3;Wroot3] + brel3 (no relu) ----
  float ginvv[2];
  #pragma unroll
  for (int mt = 0; mt < 2; mt++){
    int grow = R + (wave*2 + mt)*16 + l15;
    ginvv[mt] = 1.0f / (float)max(start[grow+1] - start[grow], 1);
  }
  floatx4 acc0[2][8] = {};
  #pragma unroll
  for (int k0 = 0; k0 < 256; k0 += 32){
    const float* Psrc = (k0 < 128) ? PM : PX;
    int kk = k0 & 127;
    int c = (k0 >> 3) + quad;
    short8 a[2];
    #pragma unroll
    for (int mt = 0; mt < 2; mt++){
      int grow = R + (wave*2 + mt)*16 + l15;
      const float* p = Psrc + grow*128 + kk + quad*8;
      float4 v0 = *(const float4*)p;
      float4 v1 = *(const float4*)(p + 4);
      float gi = ginvv[mt];
      uint4 uw = make_uint4(pack2(v0.x*gi, v0.y*gi), pack2(v0.z*gi, v0.w*gi),
                            pack2(v1.x*gi, v1.y*gi), pack2(v1.z*gi, v1.w*gi));
      a[mt] = *(short8*)&uw;
    }
    #pragma unroll
    for (int nt = 0; nt < 8; nt++){
      int n = nt*16 + l15;
      short8 b = *(const short8*)(wcat3 + n*256 + ((c ^ (n & 15)) << 3));
      #pragma unroll
      for (int mt = 0; mt < 2; mt++)
        acc0[mt][nt] = __builtin_amdgcn_mfma_f32_16x16x32_bf16(a[mt], b, acc0[mt][nt], 0, 0, 0);
    }
  }
  #pragma unroll
  for (int nt = 0; nt < 8; nt++){
    int coln = nt*16 + l15;
    float bc = brel3[coln];
    #pragma unroll
    for (int mt = 0; mt < 2; mt++){
      int lmb = (wave*2 + mt)*16 + quad*4;
      #pragma unroll
      for (int r = 0; r < 4; r++)
        Apad[(lmb + r)*APAD + coln] = f2b(acc0[mt][nt][r] + bc);
    }
  }
  __syncthreads();

  // ---- layer 1: relu(Gb @ W1 + b1), A from LDS ----
  floatx4 acc[2][8] = {};
  #pragma unroll
  for (int k0 = 0; k0 < 128; k0 += 32){
    short8 a[2];
    #pragma unroll
    for (int mt = 0; mt < 2; mt++){
      int lm = (wave*2 + mt)*16 + l15;
      a[mt] = *(const short8*)(Apad + lm*APAD + k0 + quad*8);
    }
    #pragma unroll
    for (int nt = 0; nt < 8; nt++){
      int n = nt*16 + l15;
      short8 b = *(const short8*)(wm + n*128 + k0 + quad*8);
      #pragma unroll
      for (int mt = 0; mt < 2; mt++)
        acc[mt][nt] = __builtin_amdgcn_mfma_f32_16x16x32_bf16(a[mt], b, acc[mt][nt], 0, 0, 0);
    }
  }
  __syncthreads();
  #pragma unroll
  for (int nt = 0; nt < 8; nt++){
    int coln = nt*16 + l15;
    float bc = b1[coln];
    #pragma unroll
    for (int mt = 0; mt < 2; mt++){
      int lmb = (wave*2 + mt)*16 + quad*4;
      #pragma unroll
      for (int r = 0; r < 4; r++)
        Apad[(lmb + r)*APAD + coln] = f2b(fmaxf(acc[mt][nt][r] + bc, 0.f));
    }
  }
  __syncthreads();

  // ---- layer 2: relu(h1 @ W2 + b2) ----
  floatx4 acc2[2][8] = {};
  #pragma unroll
  for (int k0 = 0; k0 < 128; k0 += 32){
    short8 a[2];
    #pragma unroll
    for (int mt = 0; mt < 2; mt++){
      int lm = (wave*2 + mt)*16 + l15;
      a[mt] = *(const short8*)(Apad + lm*APAD + k0 + quad*8);
    }
    #pragma unroll
    for (int nt = 0; nt < 8; nt++){
      int n = nt*16 + l15;
      short8 b = *(const short8*)(wm + 16384 + n*128 + k0 + quad*8);
      #pragma unroll
      for (int mt = 0; mt < 2; mt++)
        acc2[mt][nt] = __builtin_amdgcn_mfma_f32_16x16x32_bf16(a[mt], b, acc2[mt][nt], 0, 0, 0);
    }
  }
  __syncthreads();
  #pragma unroll
  for (int nt = 0; nt < 8; nt++){
    int coln = nt*16 + l15;
    float bc = b2[coln];
    #pragma unroll
    for (int mt = 0; mt < 2; mt++){
      int lmb = (wave*2 + mt)*16 + quad*4;
      #pragma unroll
      for (int r = 0; r < 4; r++)
        Apad[(lmb + r)*APAD + coln] = f2b(fmaxf(acc2[mt][nt][r] + bc, 0.f));
    }
  }
  __syncthreads();

  // ---- layer 3: h2 @ Wo + bo (f32 vector) ----
  int row = t >> 1;
  int c0  = (t & 1)*4;
  float o0 = bo[c0], o1 = bo[c0+1], o2 = bo[c0+2], o3 = bo[c0+3];
  for (int k = 0; k < 128; k++){
    float h = b2f(Apad[row*APAD + k]);
    const float* w = Wo + k*8 + c0;
    o0 = fmaf(h, w[0], o0); o1 = fmaf(h, w[1], o1);
    o2 = fmaf(h, w[2], o2); o3 = fmaf(h, w[3], o3);
  }
  float* op = out + (R + row)*8 + c0;
  op[0] = o0; op[1] = o1; op[2] = o2; op[3] = o3;
}

extern "C" void kernel_launch(void* const* d_in, const int* in_sizes, int n_in,
                              void* d_out, int out_size, void* d_ws, size_t ws_size,
                              hipStream_t stream){
  const float* x     = (const float*)d_in[0];
  const int*   ei    = (const int*)d_in[1];
  const int*   batch = (const int*)d_in[2];
  const float* Wrel1 = (const float*)d_in[3];
  const float* brel1 = (const float*)d_in[4];
  const float* Wroot1= (const float*)d_in[5];
  const float* Wrel2 = (const float*)d_in[6];
  const float* brel2 = (const float*)d_in[7];
  const float* Wroot2= (const float*)d_in[8];
  const float* Wrel3 = (const float*)d_in[9];
  const float* brel3 = (const float*)d_in[10];
  const float* Wroot3= (const float*)d_in[11];
  const float* W1 = (const float*)d_in[12]; const float* b1 = (const float*)d_in[13];
  const float* W2 = (const float*)d_in[14]; const float* b2 = (const float*)d_in[15];
  const float* Wo = (const float*)d_in[16]; const float* bo = (const float*)d_in[17];
  const int* esrc = ei;
  const int* edst = ei + N_EDGES;

  char* ws = (char*)d_ws;
  size_t off = 0;
  auto alloc = [&](size_t bytes)->char*{
    char* p = ws + off; off += (bytes + 255) & ~(size_t)255; return p;
  };
  u16*   X1     = (u16*)  alloc((size_t)N_NODES*128*2);
  u16*   X2     = (u16*)  alloc((size_t)N_NODES*128*2);
  u16*   X3     = (u16*)  alloc((size_t)N_NODES*128*2);
  u16*   Mb     = (u16*)  alloc((size_t)N_NODES*128*2);
  u16*   wcat   = (u16*)  alloc((size_t)3*128*256*2);
  u16*   wm     = (u16*)  alloc((size_t)2*128*128*2);
  float* PM     = (float*)alloc((size_t)N_GRAPHS*128*4);   // contiguous with PX
  float* PX     = (float*)alloc((size_t)N_GRAPHS*128*4);
  u32*   rp     = (u32*)  alloc((size_t)N_NODES*4);
  int*   colIdx = (int*)  alloc((size_t)NBIN*MAXBIN*4);    // doubles as rec buffer
  int*   start  = (int*)  alloc((size_t)(N_GRAPHS+1)*4);
  int*   bincur = (int*)  alloc((size_t)NBIN*4);
  u32*   rec    = (u32*)colIdx;

  dim3 b256(256);
  k_prep    <<<PREP_ZERO, b256, 0, stream>>>((const float4*)x, (uint2*)X1,
                                             Wrel1, Wroot1, Wrel2, Wroot2, Wrel3, Wroot3,
                                             wcat, W1, W2, wm, batch, start, bincur, PM);
  k_scatter2<<<NCHUNK, b256, 0, stream>>>(esrc, edst, bincur, rec);
  k_bincsr  <<<NBIN, b256, 0, stream>>>(rec, bincur, rp, colIdx);

  const int ggrid = (N_NODES + 127)/128;   // 391
  const int agrid = N_NODES/4;             // 12500

  k_aggm <<<agrid, b256, 0, stream>>>(X1, rp, colIdx, Mb);
  k_gemm2<<<ggrid, b256, 0, stream>>>(Mb, X1, wcat + 0*32768, brel1, X2);

  k_aggm <<<agrid, b256, 0, stream>>>(X2, rp, colIdx, Mb);
  k_gemm2<<<ggrid, b256, 0, stream>>>(Mb, X2, wcat + 1*32768, brel2, X3);

  k_aggm3pool<<<agrid, b256, 0, stream>>>(X3, rp, colIdx, batch, PM, PX);

  k_mlp2<<<4, b256, 0, stream>>>(PM, PX, start, wcat + 2*32768, brel3,
                                 wm, b1, b2, Wo, bo, (float*)d_out);
}

// Round 11
// 281.811 us; speedup vs baseline: 1.4021x; 1.4021x over previous
//
#include <hip/hip_runtime.h>
#include <hip/hip_bf16.h>
#include <stdint.h>

#define N_NODES  50000
#define N_EDGES  800000
#define N_GRAPHS 512

#define BINSZ   128
#define NBIN    ((N_NODES + BINSZ - 1)/BINSZ)    // 391
#define NCHUNK  256
#define CHUNK   ((N_EDGES + NCHUNK - 1)/NCHUNK)  // 3125
#define MAXBIN  3072                             // per-bin capacity (mean 2048 + 22 sigma)

typedef __attribute__((ext_vector_type(8))) short  short8;
typedef __attribute__((ext_vector_type(4))) float  floatx4;
typedef unsigned short u16;
typedef unsigned int   u32;

__device__ __forceinline__ u16 f2b(float f){
  u32 u = __float_as_uint(f);
  u = (u + 0x7FFFu + ((u >> 16) & 1u)) >> 16;   // RNE
  return (u16)u;
}
__device__ __forceinline__ u32 pack2(float a, float b){
  return (u32)f2b(a) | ((u32)f2b(b) << 16);
}
__device__ __forceinline__ float blo(u32 v){ return __uint_as_float(v << 16); }
__device__ __forceinline__ float bhi(u32 v){ return __uint_as_float(v & 0xFFFF0000u); }
__device__ __forceinline__ float b2f(u16 s){ return __uint_as_float(((u32)s) << 16); }

// ---- fused prep: cast X, prep conv/mlp weights, graph bounds, bincur init ---
#define PREP_CAST   6250
#define PREP_W2     (PREP_CAST + 256)
#define PREP_MLP    (PREP_W2 + 128)
#define PREP_BND    (PREP_MLP + 3)
#define PREP_CUR    (PREP_BND + 2)
__global__ void k_prep(const float4* __restrict__ x, uint2* __restrict__ X1,
                       const float* __restrict__ Wrel1, const float* __restrict__ Wroot1,
                       const float* __restrict__ Wrel2, const float* __restrict__ Wroot2,
                       u16* __restrict__ wcat,
                       const float* __restrict__ W1, const float* __restrict__ W2,
                       u16* __restrict__ wm,
                       const int* __restrict__ batch, int* __restrict__ start,
                       int* __restrict__ bincur){
  int blk = blockIdx.x, t = threadIdx.x;
  if (blk < PREP_CAST){
    int i = blk*256 + t;                       // exactly 1,600,000
    float4 v = x[i];
    X1[i] = make_uint2(pack2(v.x, v.y), pack2(v.z, v.w));
  } else if (blk < PREP_W2){
    int id = (blk - PREP_CAST)*256 + t;        // 65536
    int l = id >> 15;
    int r = id & 32767;
    int n = r >> 8;
    int k = r & 255;
    const float* Wrel  = l ? Wrel2  : Wrel1;
    const float* Wroot = l ? Wroot2 : Wroot1;
    float w = (k < 128) ? Wrel[k*128 + n] : Wroot[(k-128)*128 + n];
    int c = k >> 3, j = k & 7;
    wcat[l*32768 + n*256 + ((c ^ (n & 15)) << 3) + j] = f2b(w);
  } else if (blk < PREP_MLP){
    int id = (blk - PREP_W2)*256 + t;          // 32768
    int l = id >> 14;
    int r = id & 16383;
    int n = r >> 7;
    int k = r & 127;
    const float* W = l ? W2 : W1;
    wm[l*16384 + n*128 + k] = f2b(W[k*128 + n]);
  } else if (blk < PREP_BND){
    int g = (blk - PREP_MLP)*256 + t;
    if (g <= N_GRAPHS){
      int lo = 0, hi = N_NODES;
      while (lo < hi){ int mid = (lo + hi) >> 1; if (batch[mid] < g) lo = mid + 1; else hi = mid; }
      start[g] = lo;
    }
  } else {
    int i = (blk - PREP_BND)*256 + t;
    if (i < NBIN) bincur[i] = i*MAXBIN;
  }
}

// ---- CSR step 1: fused hist + range-reserve + scatter -----------------------
__launch_bounds__(256)
__global__ void k_scatter2(const int* __restrict__ src, const int* __restrict__ dst,
                           int* __restrict__ bincur, u32* __restrict__ rec){
  __shared__ int h[NBIN];
  __shared__ int cur[NBIN];
  int t = threadIdx.x;
  for (int i = t; i < NBIN; i += 256) h[i] = 0;
  __syncthreads();
  int base = blockIdx.x*CHUNK;
  int end  = min(base + CHUNK, N_EDGES);
  for (int i = base + t; i < end; i += 256) atomicAdd(&h[dst[i] >> 7], 1);
  __syncthreads();
  for (int i = t; i < NBIN; i += 256){
    int c = h[i];
    cur[i] = c ? atomicAdd(&bincur[i], c) : 0;
  }
  __syncthreads();
  for (int i = base + t; i < end; i += 256){
    int d = dst[i], sv = src[i];
    int b = d >> 7;
    int p = atomicAdd(&cur[b], 1);
    rec[p] = (u32)(((d & 127) << 16) | sv);
  }
}

// ---- CSR step 2: per-bin node-ordered segment; rp[node] = (start<<11)|deg ---
__global__ void k_bincsr(const u32* __restrict__ rec, const int* __restrict__ bincur,
                         u32* __restrict__ rp, int* __restrict__ col){
  __shared__ u32 recs[MAXBIN];
  __shared__ int colL[MAXBIN];
  __shared__ int deg[BINSZ];
  __shared__ int cursor[BINSZ];
  __shared__ int sc[BINSZ];
  int b = blockIdx.x, t = threadIdx.x;
  int s0 = b*MAXBIN;
  int n = bincur[b] - s0;
  if (t < BINSZ) deg[t] = 0;
  for (int i = t; i < n; i += 256) recs[i] = rec[s0 + i];
  __syncthreads();
  for (int i = t; i < n; i += 256) atomicAdd(&deg[(recs[i] >> 16) & 127], 1);
  __syncthreads();
  if (t < BINSZ) sc[t] = deg[t];
  __syncthreads();
  for (int off = 1; off < BINSZ; off <<= 1){
    int u = 0;
    if (t < BINSZ && t >= off) u = sc[t - off];
    __syncthreads();
    if (t < BINSZ) sc[t] += u;
    __syncthreads();
  }
  if (t < BINSZ){
    int d = deg[t];
    int pref = sc[t] - d;
    cursor[t] = pref;
    int node = b*BINSZ + t;
    if (node < N_NODES) rp[node] = (u32)((s0 + pref) << 11) | (u32)min(d, 2047);
  }
  __syncthreads();
  for (int i = t; i < n; i += 256){
    u32 r = recs[i];
    int p = atomicAdd(&cursor[(r >> 16) & 127], 1);
    colL[p] = (int)(r & 0xFFFFu);
  }
  __syncthreads();
  for (int i = t; i < n; i += 256) col[s0 + i] = colL[i];
}

// ---- Aggregation: M[i] = (1/deg) * sum_{j in N(i)} X[j]  (bf16 out) --------
// One wave per node; half-waves process alternate edges with uint2 (4ch) loads.
__global__ void k_aggm(const u16* __restrict__ X, const u32* __restrict__ rp,
                       const int* __restrict__ col, u16* __restrict__ M){
  int wave = threadIdx.x >> 6, lane = threadIdx.x & 63;
  int node = blockIdx.x*4 + wave;                 // grid covers exactly 50000
  u32 r = rp[node];
  int s = (int)(r >> 11), d = (int)(r & 2047);
  int e = s + d;
  int sub = lane >> 5, ln = lane & 31;
  const uint2* Xu = (const uint2*)X;
  float a0 = 0.f, a1 = 0.f, a2 = 0.f, a3 = 0.f;
  for (int cb = s; cb < e; cb += 64){
    int cnt = min(64, e - cb);
    int idx = 0;
    if (cb + lane < e) idx = col[cb + lane];
    int k = 0;
    for (; k + 4 <= cnt; k += 4){
      int jA = __shfl(idx, k + sub);
      int jB = __shfl(idx, k + 2 + sub);
      uint2 vA = Xu[jA*32 + ln];
      uint2 vB = Xu[jB*32 + ln];
      a0 += blo(vA.x); a1 += bhi(vA.x); a2 += blo(vA.y); a3 += bhi(vA.y);
      a0 += blo(vB.x); a1 += bhi(vB.x); a2 += blo(vB.y); a3 += bhi(vB.y);
    }
    for (; k + 2 <= cnt; k += 2){
      int j = __shfl(idx, k + sub);
      uint2 v = Xu[j*32 + ln];
      a0 += blo(v.x); a1 += bhi(v.x); a2 += blo(v.y); a3 += bhi(v.y);
    }
    if (k < cnt){
      int j = __shfl(idx, k);
      if (sub == 0){
        uint2 v = Xu[j*32 + ln];
        a0 += blo(v.x); a1 += bhi(v.x); a2 += blo(v.y); a3 += bhi(v.y);
      }
    }
  }
  a0 += __shfl_xor(a0, 32); a1 += __shfl_xor(a1, 32);
  a2 += __shfl_xor(a2, 32); a3 += __shfl_xor(a3, 32);
  if (sub == 0){
    float di = 1.0f / (float)max(d, 1);
    ((uint2*)M)[node*32 + ln] = make_uint2(pack2(a0*di, a1*di), pack2(a2*di, a3*di));
  }
}

// ---- GEMM: Xout = relu([M|X] @ Wcat2 + brel)  (M=50000, K=256, N=128) ------
__launch_bounds__(256, 2)
__global__ void k_gemm2(const u16* __restrict__ M, const u16* __restrict__ X,
                        const u16* __restrict__ Wcat, const float* __restrict__ brel,
                        u16* __restrict__ Xout){
  __shared__ u16 Bs[128*256];
  {
    const uint4* s = (const uint4*)Wcat;
    uint4* d = (uint4*)Bs;
    #pragma unroll
    for (int i = 0; i < 16; i++) d[threadIdx.x + 256*i] = s[threadIdx.x + 256*i];
  }
  __syncthreads();

  int wave = threadIdx.x >> 6, lane = threadIdx.x & 63;
  int l15 = lane & 15, quad = lane >> 4;
  int wy = wave >> 1, wx = wave & 1;
  int rowBase = blockIdx.x*128 + wy*64;

  floatx4 acc[4][4] = {};

  #pragma unroll
  for (int k0 = 0; k0 < 256; k0 += 32){
    const u16* Asrc = (k0 < 128) ? M : X;
    int kk = k0 & 127;
    int c = (k0 >> 3) + quad;
    short8 a[4];
    #pragma unroll
    for (int mt = 0; mt < 4; mt++){
      int row = rowBase + mt*16 + l15;
      if (row > N_NODES-1) row = N_NODES-1;   // clamp; stores are masked
      a[mt] = *(const short8*)(Asrc + row*128 + kk + quad*8);
    }
    #pragma unroll
    for (int nt = 0; nt < 4; nt++){
      int n = wx*64 + nt*16 + l15;
      short8 b = *(const short8*)(Bs + n*256 + ((c ^ (n & 15)) << 3));
      #pragma unroll
      for (int mt = 0; mt < 4; mt++)
        acc[mt][nt] = __builtin_amdgcn_mfma_f32_16x16x32_bf16(a[mt], b, acc[mt][nt], 0, 0, 0);
    }
  }

  float bc[4];
  #pragma unroll
  for (int nt = 0; nt < 4; nt++) bc[nt] = brel[wx*64 + nt*16 + l15];

  #pragma unroll
  for (int mt = 0; mt < 4; mt++){
    int rbase = rowBase + mt*16 + quad*4;
    #pragma unroll
    for (int r = 0; r < 4; r++){
      int row = rbase + r;
      if (row < N_NODES){
        #pragma unroll
        for (int nt = 0; nt < 4; nt++){
          int n = wx*64 + nt*16 + l15;
          Xout[row*128 + n] = f2b(fmaxf(acc[mt][nt][r] + bc[nt], 0.f));
        }
      }
    }
  }
}

// ---- fused pool + conv3 (f32 math): Gb[g] = pool(M3)@Wrel3 + pool(X3)@Wroot3 + brel3
__launch_bounds__(256)
__global__ void k_poolconv(const u16* __restrict__ M3, const u16* __restrict__ X3,
                           const int* __restrict__ start,
                           const float* __restrict__ Wrel, const float* __restrict__ Wroot,
                           const float* __restrict__ brel, u16* __restrict__ Gb){
  __shared__ float2 pm[4][64], px[4][64];
  __shared__ float pmS[128], pxS[128], part[256];
  int gid = blockIdx.x;
  int wave = threadIdx.x >> 6, lane = threadIdx.x & 63;
  int s = start[gid], e = start[gid+1];
  const u32* Mu = (const u32*)M3;
  const u32* Xu = (const u32*)X3;
  float m0 = 0.f, m1 = 0.f, x0 = 0.f, x1 = 0.f;
  for (int i = s + wave; i < e; i += 4){
    u32 vm = Mu[i*64 + lane];
    u32 vx = Xu[i*64 + lane];
    m0 += blo(vm); m1 += bhi(vm);
    x0 += blo(vx); x1 += bhi(vx);
  }
  pm[wave][lane] = make_float2(m0, m1);
  px[wave][lane] = make_float2(x0, x1);
  __syncthreads();
  if (wave == 0){
    float inv = 1.0f / (float)max(e - s, 1);
    float2 a0 = pm[0][lane], a1 = pm[1][lane], a2 = pm[2][lane], a3 = pm[3][lane];
    float2 b0 = px[0][lane], b1 = px[1][lane], b2 = px[2][lane], b3 = px[3][lane];
    pmS[2*lane]   = ((a0.x+a1.x)+(a2.x+a3.x))*inv;
    pmS[2*lane+1] = ((a0.y+a1.y)+(a2.y+a3.y))*inv;
    pxS[2*lane]   = ((b0.x+b1.x)+(b2.x+b3.x))*inv;
    pxS[2*lane+1] = ((b0.y+b1.y)+(b2.y+b3.y))*inv;
  }
  __syncthreads();
  int t = threadIdx.x;
  int n = t & 127, half = t >> 7;
  const float* W = half ? Wroot : Wrel;
  const float* S = half ? pxS : pmS;
  float a = 0.f;
  for (int k = 0; k < 128; k++) a = fmaf(S[k], W[k*128 + n], a);
  part[t] = a;
  __syncthreads();
  if (t < 128) Gb[gid*128 + t] = f2b(part[t] + part[t + 128] + brel[t]);
}

// ---- fused MLP --------------------------------------------------------------
#define APAD 136
__launch_bounds__(256)
__global__ void k_mlp(const u16* __restrict__ Gb, const u16* __restrict__ wm,
                      const float* __restrict__ b1, const float* __restrict__ b2,
                      const float* __restrict__ Wo, const float* __restrict__ bo,
                      float* __restrict__ out){
  __shared__ u16 Apad[128*APAD];
  int t = threadIdx.x;
  int wave = t >> 6, lane = t & 63;
  int l15 = lane & 15, quad = lane >> 4;
  int R = blockIdx.x*128;

  floatx4 acc[2][8] = {};
  #pragma unroll
  for (int k0 = 0; k0 < 128; k0 += 32){
    short8 a[2];
    #pragma unroll
    for (int mt = 0; mt < 2; mt++){
      int row = R + (wave*2 + mt)*16 + l15;
      a[mt] = *(const short8*)(Gb + row*128 + k0 + quad*8);
    }
    #pragma unroll
    for (int nt = 0; nt < 8; nt++){
      int n = nt*16 + l15;
      short8 b = *(const short8*)(wm + n*128 + k0 + quad*8);
      #pragma unroll
      for (int mt = 0; mt < 2; mt++)
        acc[mt][nt] = __builtin_amdgcn_mfma_f32_16x16x32_bf16(a[mt], b, acc[mt][nt], 0, 0, 0);
    }
  }
  #pragma unroll
  for (int nt = 0; nt < 8; nt++){
    int coln = nt*16 + l15;
    float bc = b1[coln];
    #pragma unroll
    for (int mt = 0; mt < 2; mt++){
      int lmb = (wave*2 + mt)*16 + quad*4;
      #pragma unroll
      for (int r = 0; r < 4; r++)
        Apad[(lmb + r)*APAD + coln] = f2b(fmaxf(acc[mt][nt][r] + bc, 0.f));
    }
  }
  __syncthreads();

  floatx4 acc2[2][8] = {};
  #pragma unroll
  for (int k0 = 0; k0 < 128; k0 += 32){
    short8 a[2];
    #pragma unroll
    for (int mt = 0; mt < 2; mt++){
      int lm = (wave*2 + mt)*16 + l15;
      a[mt] = *(const short8*)(Apad + lm*APAD + k0 + quad*8);
    }
    #pragma unroll
    for (int nt = 0; nt < 8; nt++){
      int n = nt*16 + l15;
      short8 b = *(const short8*)(wm + 16384 + n*128 + k0 + quad*8);
      #pragma unroll
      for (int mt = 0; mt < 2; mt++)
        acc2[mt][nt] = __builtin_amdgcn_mfma_f32_16x16x32_bf16(a[mt], b, acc2[mt][nt], 0, 0, 0);
    }
  }
  __syncthreads();
  #pragma unroll
  for (int nt = 0; nt < 8; nt++){
    int coln = nt*16 + l15;
    float bc = b2[coln];
    #pragma unroll
    for (int mt = 0; mt < 2; mt++){
      int lmb = (wave*2 + mt)*16 + quad*4;
      #pragma unroll
      for (int r = 0; r < 4; r++)
        Apad[(lmb + r)*APAD + coln] = f2b(fmaxf(acc2[mt][nt][r] + bc, 0.f));
    }
  }
  __syncthreads();

  int row = t >> 1;
  int c0  = (t & 1)*4;
  float o0 = bo[c0], o1 = bo[c0+1], o2 = bo[c0+2], o3 = bo[c0+3];
  for (int k = 0; k < 128; k++){
    float h = b2f(Apad[row*APAD + k]);
    const float* w = Wo + k*8 + c0;
    o0 = fmaf(h, w[0], o0); o1 = fmaf(h, w[1], o1);
    o2 = fmaf(h, w[2], o2); o3 = fmaf(h, w[3], o3);
  }
  float* op = out + (R + row)*8 + c0;
  op[0] = o0; op[1] = o1; op[2] = o2; op[3] = o3;
}

extern "C" void kernel_launch(void* const* d_in, const int* in_sizes, int n_in,
                              void* d_out, int out_size, void* d_ws, size_t ws_size,
                              hipStream_t stream){
  const float* x     = (const float*)d_in[0];
  const int*   ei    = (const int*)d_in[1];
  const int*   batch = (const int*)d_in[2];
  const float* Wrel1 = (const float*)d_in[3];
  const float* brel1 = (const float*)d_in[4];
  const float* Wroot1= (const float*)d_in[5];
  const float* Wrel2 = (const float*)d_in[6];
  const float* brel2 = (const float*)d_in[7];
  const float* Wroot2= (const float*)d_in[8];
  const float* Wrel3 = (const float*)d_in[9];
  const float* brel3 = (const float*)d_in[10];
  const float* Wroot3= (const float*)d_in[11];
  const float* W1 = (const float*)d_in[12]; const float* b1 = (const float*)d_in[13];
  const float* W2 = (const float*)d_in[14]; const float* b2 = (const float*)d_in[15];
  const float* Wo = (const float*)d_in[16]; const float* bo = (const float*)d_in[17];
  const int* esrc = ei;
  const int* edst = ei + N_EDGES;

  char* ws = (char*)d_ws;
  size_t off = 0;
  auto alloc = [&](size_t bytes)->char*{
    char* p = ws + off; off += (bytes + 255) & ~(size_t)255; return p;
  };
  u16*   X1     = (u16*)  alloc((size_t)N_NODES*128*2);
  u16*   X2     = (u16*)  alloc((size_t)N_NODES*128*2);
  u16*   X3     = (u16*)  alloc((size_t)N_NODES*128*2);
  u16*   Mb     = (u16*)  alloc((size_t)N_NODES*128*2);
  u16*   wcat   = (u16*)  alloc((size_t)2*128*256*2);
  u16*   wm     = (u16*)  alloc((size_t)2*128*128*2);
  u16*   Gb     = (u16*)  alloc((size_t)N_GRAPHS*128*2);
  u32*   rp     = (u32*)  alloc((size_t)N_NODES*4);
  int*   colIdx = (int*)  alloc((size_t)NBIN*MAXBIN*4);   // doubles as rec buffer
  int*   start  = (int*)  alloc((size_t)(N_GRAPHS+1)*4);
  int*   bincur = (int*)  alloc((size_t)NBIN*4);
  u32*   rec    = (u32*)colIdx;

  dim3 b256(256);
  k_prep    <<<PREP_CUR, b256, 0, stream>>>((const float4*)x, (uint2*)X1,
                                            Wrel1, Wroot1, Wrel2, Wroot2, wcat,
                                            W1, W2, wm, batch, start, bincur);
  k_scatter2<<<NCHUNK, b256, 0, stream>>>(esrc, edst, bincur, rec);
  k_bincsr  <<<NBIN, b256, 0, stream>>>(rec, bincur, rp, colIdx);

  const int ggrid = (N_NODES + 127)/128;   // 391
  const int agrid = N_NODES/4;             // 12500

  k_aggm <<<agrid, b256, 0, stream>>>(X1, rp, colIdx, Mb);
  k_gemm2<<<ggrid, b256, 0, stream>>>(Mb, X1, wcat + 0*32768, brel1, X2);

  k_aggm <<<agrid, b256, 0, stream>>>(X2, rp, colIdx, Mb);
  k_gemm2<<<ggrid, b256, 0, stream>>>(Mb, X2, wcat + 1*32768, brel2, X3);

  k_aggm <<<agrid, b256, 0, stream>>>(X3, rp, colIdx, Mb);

  k_poolconv<<<N_GRAPHS, b256, 0, stream>>>(Mb, X3, start, Wrel3, Wroot3, brel3, Gb);
  k_mlp     <<<4, b256, 0, stream>>>(Gb, wm, b1, b2, Wo, bo, (float*)d_out);
}